// Round 8
// baseline (297.080 us; speedup 1.0000x reference)
//
#include <hip/hip_runtime.h>

#define THREADS 256

__device__ __forceinline__ float fast_sigmoid(float v) {
    float e = __expf(-v);
    return __builtin_amdgcn_rcpf(1.0f + e);
}

// Group-G compute, compile-time G: weight indices are literal constants ->
// scalar K$ loads, hoisted. p[] = this group's 27 inputs (local indexing).
template<int G>
__device__ __forceinline__ void compute_group(
    const float* __restrict__ p,
    const float* __restrict__ Wc, const float* __restrict__ bc,
    const float* __restrict__ Wh, const float* __restrict__ bh,
    const float* __restrict__ Wm, const float* __restrict__ bm,
    const float* __restrict__ Wo, const float* __restrict__ bo,
    float& outA, float& outB)
{
    float hb[9];
    #pragma unroll
    for (int j = 0; j < 3; ++j) {
        const int g = G * 3 + j;
        float feat[9];
        #pragma unroll
        for (int k = 0; k < 9; ++k) {              // 9 independent chains -> ILP
            float acc = bc[g * 9 + k];
            #pragma unroll
            for (int pr = 0; pr < 3; ++pr)
                #pragma unroll
                for (int pc = 0; pc < 3; ++pc)
                    acc = fmaf(p[pr * 9 + j * 3 + pc],
                               Wc[(g * 9 + k) * 9 + pr * 3 + pc], acc);
            feat[k] = fast_sigmoid(acc);
        }
        #pragma unroll
        for (int n = 0; n < 3; ++n) {
            float acc = bh[g * 3 + n];
            #pragma unroll
            for (int pi = 0; pi < 9; ++pi)
                acc = fmaf(feat[pi], Wh[(g * 3 + n) * 9 + pi], acc);
            hb[j * 3 + n] = fast_sigmoid(acc);
        }
    }
    float m[4];
    #pragma unroll
    for (int n = 0; n < 4; ++n) {
        float acc = bm[G * 4 + n];
        #pragma unroll
        for (int pi = 0; pi < 9; ++pi)
            acc = fmaf(hb[pi], Wm[(G * 4 + n) * 9 + pi], acc);
        m[n] = fast_sigmoid(acc);
    }
    float acc = bo[G];
    #pragma unroll
    for (int pi = 0; pi < 4; ++pi)
        acc = fmaf(m[pi], Wo[G * 4 + pi], acc);
    outA = acc;
    if (G == 0) {                                   // class 3 reads group 0
        float acc2 = bo[3];
        #pragma unroll
        for (int pi = 0; pi < 4; ++pi)
            acc2 = fmaf(m[pi], Wo[12 + pi], acc2);
        outB = acc2;
    }
}

// R4-R7 post-mortem: every LDS-staged variant (127/117/126/150us) lost to the
// plain direct-load kernel (~100us, R0/R3). R3's fence pinned the WAIT point
// but not the ISSUE point -> loads still sank to just-before-use.
//
// R8: 2 samples/thread, 3 rotating 27-float register buffers, 6 phases.
// Each phase: {issue next buffer's 27 loads; sched_barrier(0) (pins issue
// BEFORE compute); fence current buffer (backend derives a COUNTED vmcnt
// wait); compute ~2500cy}. Only the first window's latency is exposed.
// No LDS, no clamps, no barriers.
__global__ __launch_bounds__(THREADS, 3) void olcnn_kernel(
    const float* __restrict__ x,
    const float* __restrict__ Wc, const float* __restrict__ bc,
    const float* __restrict__ Wh, const float* __restrict__ bh,
    const float* __restrict__ Wm, const float* __restrict__ bm,
    const float* __restrict__ Wo, const float* __restrict__ bo,
    float* __restrict__ out)
{
    const int tid = threadIdx.x;
    const int s0  = blockIdx.x * (THREADS * 2) + tid;   // lane-contiguous
    const int s1  = s0 + THREADS;                       // second sample
    const float* xa = x + s0 * 81;
    const float* xb = x + s1 * 81;

    float q0[27], q1[27], q2[27];

#define LOADQ(Q, SRC, G) do { _Pragma("unroll")                        \
    for (int i_ = 0; i_ < 27; ++i_) Q[i_] = (SRC)[(G) * 27 + i_]; } while (0)
#define FENCE(Q) do { _Pragma("unroll")                                \
    for (int i_ = 0; i_ < 27; ++i_) asm volatile("" : "+v"(Q[i_])); } while (0)
#define SB() __builtin_amdgcn_sched_barrier(0)

    float r0, r1, r2, r3, r4, r5, r6, r7;

    // prologue: two windows in flight (54 dwords)
    LOADQ(q0, xa, 0); LOADQ(q1, xb, 0); SB();

    // P1: issue s0.G1 under s0.G0 compute
    LOADQ(q2, xa, 1); SB();
    FENCE(q0); compute_group<0>(q0, Wc, bc, Wh, bh, Wm, bm, Wo, bo, r0, r3);

    // P2: issue s1.G1 (q0 dead after compute above; WAR kept by reg dep)
    LOADQ(q0, xb, 1); SB();
    FENCE(q1); compute_group<0>(q1, Wc, bc, Wh, bh, Wm, bm, Wo, bo, r4, r7);

    // P3: issue s0.G2
    LOADQ(q1, xa, 2); SB();
    FENCE(q2); compute_group<1>(q2, Wc, bc, Wh, bh, Wm, bm, Wo, bo, r1, r1);

    // P4: issue s1.G2
    LOADQ(q2, xb, 2); SB();
    FENCE(q0); compute_group<1>(q0, Wc, bc, Wh, bh, Wm, bm, Wo, bo, r5, r5);

    // P5/P6: drain
    SB();
    FENCE(q1); compute_group<2>(q1, Wc, bc, Wh, bh, Wm, bm, Wo, bo, r2, r2);
    FENCE(q2); compute_group<2>(q2, Wc, bc, Wh, bh, Wm, bm, Wo, bo, r6, r6);

#undef LOADQ
#undef FENCE
#undef SB

    float4 oA; oA.x = r0; oA.y = r1; oA.z = r2; oA.w = r3;
    float4 oB; oB.x = r4; oB.y = r5; oB.z = r6; oB.w = r7;
    ((float4*)out)[s0] = oA;                        // coalesced 16B/lane
    ((float4*)out)[s1] = oB;
}

extern "C" void kernel_launch(void* const* d_in, const int* in_sizes, int n_in,
                              void* d_out, int out_size, void* d_ws, size_t ws_size,
                              hipStream_t stream) {
    const float* x  = (const float*)d_in[0];
    const float* Wc = (const float*)d_in[1];
    const float* bc = (const float*)d_in[2];
    const float* Wh = (const float*)d_in[3];
    const float* bh = (const float*)d_in[4];
    const float* Wm = (const float*)d_in[5];
    const float* bm = (const float*)d_in[6];
    const float* Wo = (const float*)d_in[7];
    const float* bo = (const float*)d_in[8];
    float* out = (float*)d_out;

    const int B = in_sizes[0] / 81;                // 524288
    const int blocks = B / (THREADS * 2);          // 1024 (exact)
    olcnn_kernel<<<blocks, THREADS, 0, stream>>>(x, Wc, bc, Wh, bh, Wm, bm,
                                                 Wo, bo, out);
}